// Round 1
// baseline (950.055 us; speedup 1.0000x reference)
//
#include <hip/hip_runtime.h>

// LMFreezeConcatModel: lm = X@W_lm+b ; 3x GCNConv(sym-norm, self-loops) ; concat -> W_cls.
// This revision: norm folded into GEMM epilogue (no wn array), whole-tile
// global_load_lds GCN GEMMs with XOR-swizzled LDS, shfl-broadcast aggregation,
// classifier fused into the final aggregate.

using bf16x8 = __attribute__((ext_vector_type(8))) short;
using f32x4  = __attribute__((ext_vector_type(4))) float;
typedef unsigned short u16;
typedef unsigned int   u32;

__device__ __forceinline__ u16 f2bf(float f) {
  u32 u = __builtin_bit_cast(u32, f);
  u += 0x7fffu + ((u >> 16) & 1u);          // round-to-nearest-even
  return (u16)(u >> 16);
}
__device__ __forceinline__ float bf2f(u32 lo16) {
  return __builtin_bit_cast(float, lo16 << 16);
}
__device__ __forceinline__ u32 packbf2(float a, float b) {
  u32 r;                                     // lo = bf16(a), hi = bf16(b), RNE
  asm("v_cvt_pk_bf16_f32 %0, %1, %2" : "=v"(r) : "v"(a), "v"(b));
  return r;
}
__device__ __forceinline__ void gl_lds16(const void* g, void* l) {
  __builtin_amdgcn_global_load_lds(
      (const __attribute__((address_space(1))) void*)g,
      (__attribute__((address_space(3))) void*)l, 16, 0, 0);
}

// ---------------- degree / CSR build ----------------

__global__ void count_kernel(const int* __restrict__ dst, int* __restrict__ counts, int E) {
  int e = blockIdx.x * 256 + threadIdx.x;
  if (e < E) atomicAdd(&counts[dst[e]], 1);
}

__global__ void dinv_kernel(const int* __restrict__ counts, float* __restrict__ dinv, int N) {
  int i = blockIdx.x * 256 + threadIdx.x;
  if (i < N) dinv[i] = rsqrtf((float)(counts[i] + 1));   // +1 self-loop; deg>=1 always
}

// two-level exclusive scan over counts[N] -> offsets[N]
__global__ void scan_partial(const int* __restrict__ counts, int* __restrict__ partials, int N) {
  __shared__ int sdata[256];
  int t = threadIdx.x;
  int base = blockIdx.x * 1024 + t * 4;
  int s = 0;
#pragma unroll
  for (int i = 0; i < 4; i++) { int idx = base + i; if (idx < N) s += counts[idx]; }
  sdata[t] = s; __syncthreads();
  for (int off = 128; off > 0; off >>= 1) {
    if (t < off) sdata[t] += sdata[t + off];
    __syncthreads();
  }
  if (t == 0) partials[blockIdx.x] = sdata[0];
}

__global__ void scan_partials_excl(int* __restrict__ partials, int NB,
                                   int* __restrict__ offsets, int N, int E) {
  __shared__ int sdata[256];
  int t = threadIdx.x;
  int v = (t < NB) ? partials[t] : 0;
  sdata[t] = v; __syncthreads();
  int val = v;
  for (int off = 1; off < 256; off <<= 1) {
    int add = (t >= off) ? sdata[t - off] : 0;
    __syncthreads();
    val += add; sdata[t] = val;
    __syncthreads();
  }
  if (t < NB) partials[t] = val - v;   // exclusive
  if (t == 0) offsets[N] = E;
}

__global__ void scan_final(const int* __restrict__ counts, const int* __restrict__ partials,
                           int* __restrict__ offsets, int N) {
  __shared__ int sdata[256];
  int t = threadIdx.x;
  int base = blockIdx.x * 1024 + t * 4;
  int v[4]; int tsum = 0;
#pragma unroll
  for (int i = 0; i < 4; i++) { int idx = base + i; v[i] = (idx < N) ? counts[idx] : 0; tsum += v[i]; }
  sdata[t] = tsum; __syncthreads();
  int val = tsum;
  for (int off = 1; off < 256; off <<= 1) {
    int add = (t >= off) ? sdata[t - off] : 0;
    __syncthreads();
    val += add; sdata[t] = val;
    __syncthreads();
  }
  int run = partials[blockIdx.x] + val - tsum;
#pragma unroll
  for (int i = 0; i < 4; i++) { int idx = base + i; if (idx < N) offsets[idx] = run; run += v[i]; }
}

__global__ void fill_kernel(const int* __restrict__ src, const int* __restrict__ dst,
                            const int* __restrict__ offsets, int* __restrict__ cursor,
                            int* __restrict__ col, int E) {
  int e = blockIdx.x * 256 + threadIdx.x;
  if (e < E) {
    int d = dst[e];
    int p = offsets[d] + atomicAdd(&cursor[d], 1);
    col[p] = src[e];                        // norm folded into h' rows; no wn array
  }
}

// ---------------- weight prep (transpose + bf16) ----------------

__global__ void prep_wlm(const float* __restrict__ W, u16* __restrict__ Wt) {
  int idx = blockIdx.x * 256 + threadIdx.x;       // over 1024*128
  if (idx < 1024 * 128) {
    int k = idx >> 7, c = idx & 127;
    Wt[c * 1024 + k] = f2bf(W[idx]);              // Wt[col][k]
  }
}
__global__ void prep_wgcn(const float* __restrict__ W, u16* __restrict__ Wt, int total) {
  int idx = blockIdx.x * 256 + threadIdx.x;       // over L*128*128
  if (idx < total) {
    int l = idx >> 14; int r = idx & 16383;
    int k = r >> 7, c = r & 127;
    Wt[l * 16384 + c * 128 + k] = f2bf(W[idx]);
  }
}

// ---------------- lm GEMM: Out[N][128] = bf16(A_f32[N][1024] @ B[1024][128] + bias) ----------
// BM=128 BN=128 BK=32, 4 waves. A reg-staged (f32->bf16 cvt_pk), B via global_load_lds.
// LDS tiles 16B-chunk XOR-swizzled (chunk ^= row&3): frag-read conflicts 8-way -> 4-way.

__global__ __launch_bounds__(256) void gemm_lm_kernel(
    const float* __restrict__ A, const u16* __restrict__ Bt,
    const float* __restrict__ bias, u16* __restrict__ Out, int Nrows)
{
  __shared__ u16 lA[128 * 32];
  __shared__ u16 lB[128 * 32];
  const int t = threadIdx.x;
  const int lane = t & 63;
  const int w = t >> 6;
  const int wr = w >> 1, wc = w & 1;
  const int row0 = blockIdx.x * 128;
  const int quad = lane >> 4;
  const int l16 = lane & 15;

  f32x4 acc[4][4];
#pragma unroll
  for (int i = 0; i < 4; i++)
#pragma unroll
    for (int j = 0; j < 4; j++) acc[i][j] = f32x4{0.f, 0.f, 0.f, 0.f};

  for (int k0 = 0; k0 < 1024; k0 += 32) {
    // --- B tile: global_load_lds, linear LDS dest + inverse-swizzled source ---
#pragma unroll
    for (int rpt = 0; rpt < 2; rpt++) {
      int seg = t + rpt * 256;
      int c = seg >> 2;                     // 4 x 16B chunks per 64B row
      int ch = (seg & 3) ^ (c & 3);         // pre-swizzled source chunk
      gl_lds16((const char*)Bt + (size_t)c * 2048 + (size_t)k0 * 2 + ch * 16,
               (char*)lB + seg * 16);
    }
    // --- A tile: f32 -> bf16 pack in regs, swizzled ds_write ---
#pragma unroll
    for (int rpt = 0; rpt < 2; rpt++) {
      int seg = t + rpt * 256;
      int row = seg >> 2, ks = seg & 3;
      int grow = row0 + row; if (grow >= Nrows) grow = Nrows - 1;
      const float* gp = A + (size_t)grow * 1024 + k0 + ks * 8;
      float4 f0 = *reinterpret_cast<const float4*>(gp);
      float4 f1 = *reinterpret_cast<const float4*>(gp + 4);
      uint4 pk;
      pk.x = packbf2(f0.x, f0.y); pk.y = packbf2(f0.z, f0.w);
      pk.z = packbf2(f1.x, f1.y); pk.w = packbf2(f1.z, f1.w);
      *reinterpret_cast<uint4*>((char*)lA + ((seg * 16) ^ ((row & 3) << 4))) = pk;
    }
    __syncthreads();

    bf16x8 af[4], bfr[4];
#pragma unroll
    for (int i = 0; i < 4; i++) {
      int r = wr * 64 + i * 16 + l16;
      af[i] = *reinterpret_cast<const bf16x8*>(
          (const char*)lA + r * 64 + ((quad ^ (r & 3)) << 4));
    }
#pragma unroll
    for (int j = 0; j < 4; j++) {
      int c = wc * 64 + j * 16 + l16;
      bfr[j] = *reinterpret_cast<const bf16x8*>(
          (const char*)lB + c * 64 + ((quad ^ (c & 3)) << 4));
    }
    __syncthreads();   // frags in regs; next-iter staging may overwrite after this

#pragma unroll
    for (int i = 0; i < 4; i++)
#pragma unroll
      for (int j = 0; j < 4; j++)
        acc[i][j] = __builtin_amdgcn_mfma_f32_16x16x32_bf16(af[i], bfr[j], acc[i][j], 0, 0, 0);
  }

  // epilogue: C/D layout col=lane&15, row=quad*4+reg
#pragma unroll
  for (int i = 0; i < 4; i++) {
    int rbase = row0 + wr * 64 + i * 16 + quad * 4;
#pragma unroll
    for (int j = 0; j < 4; j++) {
      int c = wc * 64 + j * 16 + l16;
      float bv = bias[c];
#pragma unroll
      for (int r = 0; r < 4; r++) {
        int grow = rbase + r;
        if (grow < Nrows)
          Out[(size_t)grow * 128 + c] = f2bf(acc[i][j][r] + bv);
      }
    }
  }
}

// ---------------- GCN GEMM: Out[N][128] = bf16( dinv[row] * (A[N][128] @ B[128][128]) ) ----
// K=128: whole A tile (32KB) + whole B (32KB) in LDS, ONE barrier per block.
// 256B rows => linear would be 16-way bank conflict; chunk ^= row&15 makes reads 2-way (free).

__global__ __launch_bounds__(256) void gemm128_kernel(
    const u16* __restrict__ A, const u16* __restrict__ Bt,
    const float* __restrict__ rs, u16* __restrict__ Out, int Nrows)
{
  __shared__ u16 lA[128 * 128];
  __shared__ u16 lB[128 * 128];
  const int t = threadIdx.x;
  const int lane = t & 63;
  const int w = t >> 6;
  const int wr = w >> 1, wc = w & 1;
  const int row0 = blockIdx.x * 128;
  const int quad = lane >> 4;
  const int l16 = lane & 15;

  // stage both tiles via global_load_lds: linear LDS dest, pre-swizzled global source
#pragma unroll
  for (int rp = 0; rp < 8; rp++) {
    int o = (t + rp * 256) * 16;            // linear LDS byte offset
    int row = o >> 8;                       // 256B per row (128 x bf16)
    int io = (o ^ ((row & 15) << 4)) & 255; // swizzled intra-row byte offset
    long grow = (long)row0 + row;
    if (grow >= Nrows) grow = Nrows - 1;    // clamp: no OOB reads on tail block
    gl_lds16((const char*)A + grow * 256 + io, (char*)lA + o);
    gl_lds16((const char*)Bt + row * 256 + io, (char*)lB + o);
  }
  __syncthreads();

  f32x4 acc[4][4];
#pragma unroll
  for (int i = 0; i < 4; i++)
#pragma unroll
    for (int j = 0; j < 4; j++) acc[i][j] = f32x4{0.f, 0.f, 0.f, 0.f};

#pragma unroll
  for (int kk = 0; kk < 4; kk++) {
    bf16x8 af[4], bfr[4];
#pragma unroll
    for (int i = 0; i < 4; i++) {
      int r = wr * 64 + i * 16 + l16;
      int ch = (kk * 4 + quad) ^ (r & 15);
      af[i] = *reinterpret_cast<const bf16x8*>((const char*)lA + r * 256 + ch * 16);
    }
#pragma unroll
    for (int j = 0; j < 4; j++) {
      int c = wc * 64 + j * 16 + l16;
      int ch = (kk * 4 + quad) ^ (c & 15);
      bfr[j] = *reinterpret_cast<const bf16x8*>((const char*)lB + c * 256 + ch * 16);
    }
#pragma unroll
    for (int i = 0; i < 4; i++)
#pragma unroll
      for (int j = 0; j < 4; j++)
        acc[i][j] = __builtin_amdgcn_mfma_f32_16x16x32_bf16(af[i], bfr[j], acc[i][j], 0, 0, 0);
  }

  // epilogue: scale rows by dinv (folds the src-side sym-norm into h')
#pragma unroll
  for (int i = 0; i < 4; i++) {
    int rbase = row0 + wr * 64 + i * 16 + quad * 4;
#pragma unroll
    for (int r = 0; r < 4; r++) {
      int grow = rbase + r;
      if (grow < Nrows) {
        float sc = rs[grow];
#pragma unroll
        for (int j = 0; j < 4; j++) {
          int c = wc * 64 + j * 16 + l16;
          Out[(size_t)grow * 128 + c] = f2bf(acc[i][j][r] * sc);
        }
      }
    }
  }
}

// ---------------- aggregation (+ fused classifier on final layer) ----------------
// h rows are pre-scaled h'[j] = dinv[j]*h[j].
// out[i] = relu( dinv[i] * ( sum_{e:dst=i} h'[col[e]] + h'[i] ) + b )
// One wave per dst row; col indices loaded coalesced (64/load) and shfl-broadcast,
// so gathers have no per-edge load->load address dependency chain.
// FINAL: logits[i] = concat(lm[i], out[i]) @ Wc + bc via per-lane partials + butterfly.

#define BRED(v) do { v += __shfl_xor(v, 1);  v += __shfl_xor(v, 2);  v += __shfl_xor(v, 4); \
                     v += __shfl_xor(v, 8);  v += __shfl_xor(v, 16); v += __shfl_xor(v, 32); } while (0)

template<bool FINAL>
__global__ __launch_bounds__(256) void aggregate_kernel(
    const u16* __restrict__ h, const int* __restrict__ offsets,
    const int* __restrict__ col, const float* __restrict__ dinv,
    const float* __restrict__ bias, u16* __restrict__ outf,
    const u16* __restrict__ lm, const float* __restrict__ Wc,
    const float* __restrict__ bc, float* __restrict__ logits, int N)
{
  int w = threadIdx.x >> 6;
  int lane = threadIdx.x & 63;
  int i = blockIdx.x * 4 + w;
  if (i >= N) return;
  const u32* h32 = (const u32*)h;
  u32 us = h32[(size_t)i * 64 + lane];               // self term h'[i]
  float ax = bf2f(us & 0xffffu), ay = bf2f(us >> 16);
  int s = offsets[i], e = offsets[i + 1];
  for (int base = s; base < e; base += 64) {
    int cnt = e - base; if (cnt > 64) cnt = 64;
    int cj = (base + lane < e) ? col[base + lane] : 0;   // one coalesced load per 64 edges
    int k = 0;
    for (; k + 4 <= cnt; k += 4) {                       // batch-4 gathers for MLP
      int j0 = __shfl(cj, k),     j1 = __shfl(cj, k + 1);
      int j2 = __shfl(cj, k + 2), j3 = __shfl(cj, k + 3);
      u32 u0 = h32[(size_t)j0 * 64 + lane];
      u32 u1 = h32[(size_t)j1 * 64 + lane];
      u32 u2 = h32[(size_t)j2 * 64 + lane];
      u32 u3 = h32[(size_t)j3 * 64 + lane];
      ax += bf2f(u0 & 0xffffu); ay += bf2f(u0 >> 16);
      ax += bf2f(u1 & 0xffffu); ay += bf2f(u1 >> 16);
      ax += bf2f(u2 & 0xffffu); ay += bf2f(u2 >> 16);
      ax += bf2f(u3 & 0xffffu); ay += bf2f(u3 >> 16);
    }
    for (; k < cnt; k++) {
      int j = __shfl(cj, k);
      u32 uu = h32[(size_t)j * 64 + lane];
      ax += bf2f(uu & 0xffffu); ay += bf2f(uu >> 16);
    }
  }
  float di = dinv[i];
  ax = fmaxf(ax * di + bias[lane * 2], 0.f);
  ay = fmaxf(ay * di + bias[lane * 2 + 1], 0.f);
  if (!FINAL) {
    ((u32*)outf)[(size_t)i * 64 + lane] = packbf2(ax, ay);
  } else {
    u32 ul = ((const u32*)lm)[(size_t)i * 64 + lane];
    float lx = bf2f(ul & 0xffffu), ly = bf2f(ul >> 16);
    const float4* W4 = (const float4*)Wc;              // Wc[256][8], 32B per row
    float4 a0 = W4[(2 * lane) * 2],       a1 = W4[(2 * lane) * 2 + 1];        // lm row 2l
    float4 b0 = W4[(2 * lane + 1) * 2],   b1 = W4[(2 * lane + 1) * 2 + 1];    // lm row 2l+1
    float4 c0 = W4[(128 + 2 * lane) * 2], c1 = W4[(128 + 2 * lane) * 2 + 1];  // out row 2l
    float4 d0 = W4[(129 + 2 * lane) * 2], d1 = W4[(129 + 2 * lane) * 2 + 1];  // out row 2l+1
    float s0 = lx * a0.x + ly * b0.x + ax * c0.x + ay * d0.x;
    float s1 = lx * a0.y + ly * b0.y + ax * c0.y + ay * d0.y;
    float s2 = lx * a0.z + ly * b0.z + ax * c0.z + ay * d0.z;
    float s3 = lx * a0.w + ly * b0.w + ax * c0.w + ay * d0.w;
    float s4 = lx * a1.x + ly * b1.x + ax * c1.x + ay * d1.x;
    float s5 = lx * a1.y + ly * b1.y + ax * c1.y + ay * d1.y;
    float s6 = lx * a1.z + ly * b1.z + ax * c1.z + ay * d1.z;
    float s7 = lx * a1.w + ly * b1.w + ax * c1.w + ay * d1.w;
    BRED(s0); BRED(s1); BRED(s2); BRED(s3); BRED(s4); BRED(s5); BRED(s6); BRED(s7);
    if (lane < 8) {
      float v = s0;
      v = (lane == 1) ? s1 : v;
      v = (lane == 2) ? s2 : v;
      v = (lane == 3) ? s3 : v;
      v = (lane == 4) ? s4 : v;
      v = (lane == 5) ? s5 : v;
      v = (lane == 6) ? s6 : v;
      v = (lane == 7) ? s7 : v;
      logits[(size_t)i * 8 + lane] = v + bc[lane];
    }
  }
}
#undef BRED

// ---------------- launcher ----------------

static inline char* bump(char*& p, size_t bytes) {
  char* r = p;
  p += (bytes + 255) & ~(size_t)255;
  return r;
}

extern "C" void kernel_launch(void* const* d_in, const int* in_sizes, int n_in,
                              void* d_out, int out_size, void* d_ws, size_t ws_size,
                              hipStream_t stream) {
  const float* X   = (const float*)d_in[0];   // [N][1024]
  const int*   EI  = (const int*)  d_in[1];   // [2][E]
  const float* Wlm = (const float*)d_in[2];   // [1024][128]
  const float* blm = (const float*)d_in[3];   // [128]
  const float* Wg  = (const float*)d_in[4];   // [L][128][128]
  const float* bg  = (const float*)d_in[5];   // [L][128]
  const float* Wc  = (const float*)d_in[6];   // [256][8]
  const float* bc  = (const float*)d_in[7];   // [8]
  float* out = (float*)d_out;

  const int N = in_sizes[0] / 1024;
  const int E = in_sizes[1] / 2;
  const int L = in_sizes[4] / (128 * 128);

  char* wp = (char*)d_ws;
  int*   counts  = (int*)  bump(wp, (size_t)N * 4);
  int*   cursor  = (int*)  bump(wp, (size_t)N * 4);
  int*   offs    = (int*)  bump(wp, (size_t)(N + 1) * 4);
  float* dinv    = (float*)bump(wp, (size_t)N * 4);
  int*   partials= (int*)  bump(wp, 1024 * 4);
  int*   colA    = (int*)  bump(wp, (size_t)E * 4);
  u16*   WlmT    = (u16*)  bump(wp, (size_t)1024 * 128 * 2);
  u16*   WgT     = (u16*)  bump(wp, (size_t)L * 128 * 128 * 2);
  u16*   lmB     = (u16*)  bump(wp, (size_t)N * 128 * 2);
  u16*   hB      = (u16*)  bump(wp, (size_t)N * 128 * 2);
  u16*   featB   = (u16*)  bump(wp, (size_t)N * 128 * 2);

  hipMemsetAsync(counts, 0, (size_t)N * 4, stream);
  hipMemsetAsync(cursor, 0, (size_t)N * 4, stream);

  const int* srcp = EI;
  const int* dstp = EI + E;

  count_kernel<<<(E + 255) / 256, 256, 0, stream>>>(dstp, counts, E);
  dinv_kernel<<<(N + 255) / 256, 256, 0, stream>>>(counts, dinv, N);

  int NB = (N + 1023) / 1024;   // 98 for N=100000; single-block scan supports NB<=256
  scan_partial<<<NB, 256, 0, stream>>>(counts, partials, N);
  scan_partials_excl<<<1, 256, 0, stream>>>(partials, NB, offs, N, E);
  scan_final<<<NB, 256, 0, stream>>>(counts, partials, offs, N);
  fill_kernel<<<(E + 255) / 256, 256, 0, stream>>>(srcp, dstp, offs, cursor, colA, E);

  prep_wlm<<<(1024 * 128 + 255) / 256, 256, 0, stream>>>(Wlm, WlmT);
  prep_wgcn<<<(L * 128 * 128 + 255) / 256, 256, 0, stream>>>(Wg, WgT, L * 128 * 128);

  int GB = (N + 127) / 128;
  gemm_lm_kernel<<<GB, 256, 0, stream>>>(X, WlmT, blm, lmB, N);

  const u16* cur = lmB;
  for (int l = 0; l < L; l++) {
    gemm128_kernel<<<GB, 256, 0, stream>>>(cur, WgT + (size_t)l * 16384, dinv, hB, N);
    if (l < L - 1) {
      aggregate_kernel<false><<<(N + 3) / 4, 256, 0, stream>>>(
          hB, offs, colA, dinv, bg + (size_t)l * 128, featB,
          nullptr, nullptr, nullptr, nullptr, N);
      cur = featB;
    } else {
      aggregate_kernel<true><<<(N + 3) / 4, 256, 0, stream>>>(
          hB, offs, colA, dinv, bg + (size_t)l * 128, nullptr,
          lmB, Wc, bc, out, N);
    }
  }
}

// Round 3
// 938.311 us; speedup vs baseline: 1.0125x; 1.0125x over previous
//
#include <hip/hip_runtime.h>

// LMFreezeConcatModel: lm = X@W_lm+b ; 3x GCNConv(sym-norm, self-loops) ; concat -> W_cls.
// This revision: lm GEMM rebuilt as single-barrier double-buffered pipeline with
// depth-2 A-register prefetch + counted vmcnt(4) barriers (T3/T4); CSR fill via
// atomicSub on counts (cursor array + its memset removed).

using bf16x8 = __attribute__((ext_vector_type(8))) short;
using f32x4  = __attribute__((ext_vector_type(4))) float;
typedef unsigned short u16;
typedef unsigned int   u32;

__device__ __forceinline__ u16 f2bf(float f) {
  u32 u = __builtin_bit_cast(u32, f);
  u += 0x7fffu + ((u >> 16) & 1u);          // round-to-nearest-even
  return (u16)(u >> 16);
}
__device__ __forceinline__ float bf2f(u32 lo16) {
  return __builtin_bit_cast(float, lo16 << 16);
}
__device__ __forceinline__ u32 packbf2(float a, float b) {
  u32 r;                                     // lo = bf16(a), hi = bf16(b), RNE
  asm("v_cvt_pk_bf16_f32 %0, %1, %2" : "=v"(r) : "v"(a), "v"(b));
  return r;
}
__device__ __forceinline__ void gl_lds16(const void* g, void* l) {
  __builtin_amdgcn_global_load_lds(
      (const __attribute__((address_space(1))) void*)g,
      (__attribute__((address_space(3))) void*)l, 16, 0, 0);
}

// ---------------- degree / CSR build ----------------

__global__ void count_kernel(const int* __restrict__ dst, int* __restrict__ counts, int E) {
  int e = blockIdx.x * 256 + threadIdx.x;
  if (e < E) atomicAdd(&counts[dst[e]], 1);
}

__global__ void dinv_kernel(const int* __restrict__ counts, float* __restrict__ dinv, int N) {
  int i = blockIdx.x * 256 + threadIdx.x;
  if (i < N) dinv[i] = rsqrtf((float)(counts[i] + 1));   // +1 self-loop; deg>=1 always
}

// two-level exclusive scan over counts[N] -> offsets[N]
__global__ void scan_partial(const int* __restrict__ counts, int* __restrict__ partials, int N) {
  __shared__ int sdata[256];
  int t = threadIdx.x;
  int base = blockIdx.x * 1024 + t * 4;
  int s = 0;
#pragma unroll
  for (int i = 0; i < 4; i++) { int idx = base + i; if (idx < N) s += counts[idx]; }
  sdata[t] = s; __syncthreads();
  for (int off = 128; off > 0; off >>= 1) {
    if (t < off) sdata[t] += sdata[t + off];
    __syncthreads();
  }
  if (t == 0) partials[blockIdx.x] = sdata[0];
}

__global__ void scan_partials_excl(int* __restrict__ partials, int NB,
                                   int* __restrict__ offsets, int N, int E) {
  __shared__ int sdata[256];
  int t = threadIdx.x;
  int v = (t < NB) ? partials[t] : 0;
  sdata[t] = v; __syncthreads();
  int val = v;
  for (int off = 1; off < 256; off <<= 1) {
    int add = (t >= off) ? sdata[t - off] : 0;
    __syncthreads();
    val += add; sdata[t] = val;
    __syncthreads();
  }
  if (t < NB) partials[t] = val - v;   // exclusive
  if (t == 0) offsets[N] = E;
}

__global__ void scan_final(const int* __restrict__ counts, const int* __restrict__ partials,
                           int* __restrict__ offsets, int N) {
  __shared__ int sdata[256];
  int t = threadIdx.x;
  int base = blockIdx.x * 1024 + t * 4;
  int v[4]; int tsum = 0;
#pragma unroll
  for (int i = 0; i < 4; i++) { int idx = base + i; v[i] = (idx < N) ? counts[idx] : 0; tsum += v[i]; }
  sdata[t] = tsum; __syncthreads();
  int val = tsum;
  for (int off = 1; off < 256; off <<= 1) {
    int add = (t >= off) ? sdata[t - off] : 0;
    __syncthreads();
    val += add; sdata[t] = val;
    __syncthreads();
  }
  int run = partials[blockIdx.x] + val - tsum;
#pragma unroll
  for (int i = 0; i < 4; i++) { int idx = base + i; if (idx < N) offsets[idx] = run; run += v[i]; }
}

// fill claims slots by decrementing counts (degree) -> positions offs[d]..offs[d]+deg-1.
// counts is dead after dinv_kernel, so no separate cursor array / memset needed.
__global__ void fill_kernel(const int* __restrict__ src, const int* __restrict__ dst,
                            const int* __restrict__ offsets, int* __restrict__ counts,
                            int* __restrict__ col, int E) {
  int e = blockIdx.x * 256 + threadIdx.x;
  if (e < E) {
    int d = dst[e];
    int p = offsets[d] + atomicSub(&counts[d], 1) - 1;
    col[p] = src[e];
  }
}

// ---------------- weight prep (transpose + bf16) ----------------

__global__ void prep_wlm(const float* __restrict__ W, u16* __restrict__ Wt) {
  int idx = blockIdx.x * 256 + threadIdx.x;       // over 1024*128
  if (idx < 1024 * 128) {
    int k = idx >> 7, c = idx & 127;
    Wt[c * 1024 + k] = f2bf(W[idx]);              // Wt[col][k]
  }
}
__global__ void prep_wgcn(const float* __restrict__ W, u16* __restrict__ Wt, int total) {
  int idx = blockIdx.x * 256 + threadIdx.x;       // over L*128*128
  if (idx < total) {
    int l = idx >> 14; int r = idx & 16383;
    int k = r >> 7, c = r & 127;
    Wt[l * 16384 + c * 128 + k] = f2bf(W[idx]);
  }
}

// ---------------- lm GEMM: Out[N][128] = bf16(A_f32[N][1024] @ B[1024][128] + bias) ----------
// BM=128 BN=128 BK=32, 4 waves. Pipeline: LDS double-buffered, ONE barrier per K-step,
// depth-2 register prefetch of the A f32 tile, counted s_waitcnt vmcnt(4) before s_barrier
// so the next K-step's 4 A-loads stay in flight across the barrier (only B's 2
// global_load_lds must land). 16B-chunk XOR swizzle on both tiles (4-way max conflict).

__global__ __launch_bounds__(256) void gemm_lm_kernel(
    const float* __restrict__ A, const u16* __restrict__ Bt,
    const float* __restrict__ bias, u16* __restrict__ Out, int Nrows)
{
  __shared__ u16 lA[2][128 * 32];
  __shared__ u16 lB[2][128 * 32];
  const int t = threadIdx.x;
  const int lane = t & 63;
  const int w = t >> 6;
  const int wr = w >> 1, wc = w & 1;
  const long rowbase = (long)blockIdx.x * 128;
  const int quad = lane >> 4;
  const int l16 = lane & 15;

  // per-thread staging geometry: 2 segments (t, t+256); seg>>2 = row/col, seg&3 = k-chunk
  const int seg0 = t, seg1 = t + 256;
  const int r0 = seg0 >> 2, kq0 = seg0 & 3;
  const int r1 = seg1 >> 2, kq1 = seg1 & 3;
  long g0 = rowbase + r0; if (g0 >= Nrows) g0 = Nrows - 1;
  long g1 = rowbase + r1; if (g1 >= Nrows) g1 = Nrows - 1;
  const float* Ab0 = A + g0 * 1024 + kq0 * 8;
  const float* Ab1 = A + g1 * 1024 + kq1 * 8;
  const int dA0 = (seg0 * 16) ^ ((r0 & 3) << 4);
  const int dA1 = (seg1 * 16) ^ ((r1 & 3) << 4);
  const char* Bsrc0 = (const char*)Bt + (size_t)r0 * 2048 + ((kq0 ^ (r0 & 3)) << 4);
  const char* Bsrc1 = (const char*)Bt + (size_t)r1 * 2048 + ((kq1 ^ (r1 & 3)) << 4);
  const int dB0 = seg0 * 16, dB1 = seg1 * 16;

  f32x4 acc[4][4];
#pragma unroll
  for (int i = 0; i < 4; i++)
#pragma unroll
    for (int j = 0; j < 4; j++) acc[i][j] = f32x4{0.f, 0.f, 0.f, 0.f};

  float4 fa[2][4];   // A prefetch register sets; indices are macro-literal constants only

#define GLB(KS, BUF) do { \
    gl_lds16(Bsrc0 + (size_t)(KS) * 64, (char*)lB[BUF] + dB0); \
    gl_lds16(Bsrc1 + (size_t)(KS) * 64, (char*)lB[BUF] + dB1); \
  } while (0)

#define ALOAD(KS, S) do { \
    fa[S][0] = *reinterpret_cast<const float4*>(Ab0 + (KS) * 32); \
    fa[S][1] = *reinterpret_cast<const float4*>(Ab0 + (KS) * 32 + 4); \
    fa[S][2] = *reinterpret_cast<const float4*>(Ab1 + (KS) * 32); \
    fa[S][3] = *reinterpret_cast<const float4*>(Ab1 + (KS) * 32 + 4); \
  } while (0)

#define APACK(S, BUF) do { \
    uint4 pk0, pk1; \
    pk0.x = packbf2(fa[S][0].x, fa[S][0].y); pk0.y = packbf2(fa[S][0].z, fa[S][0].w); \
    pk0.z = packbf2(fa[S][1].x, fa[S][1].y); pk0.w = packbf2(fa[S][1].z, fa[S][1].w); \
    pk1.x = packbf2(fa[S][2].x, fa[S][2].y); pk1.y = packbf2(fa[S][2].z, fa[S][2].w); \
    pk1.z = packbf2(fa[S][3].x, fa[S][3].y); pk1.w = packbf2(fa[S][3].z, fa[S][3].w); \
    *reinterpret_cast<uint4*>((char*)lA[BUF] + dA0) = pk0; \
    *reinterpret_cast<uint4*>((char*)lA[BUF] + dA1) = pk1; \
  } while (0)

#define FRAGS(BUF) do { \
    _Pragma("unroll") \
    for (int i = 0; i < 4; i++) { \
      int r = wr * 64 + i * 16 + l16; \
      af[i] = *reinterpret_cast<const bf16x8*>( \
          (const char*)lA[BUF] + r * 64 + ((quad ^ (r & 3)) << 4)); \
    } \
    _Pragma("unroll") \
    for (int j = 0; j < 4; j++) { \
      int c = wc * 64 + j * 16 + l16; \
      bfr[j] = *reinterpret_cast<const bf16x8*>( \
          (const char*)lB[BUF] + c * 64 + ((quad ^ (c & 3)) << 4)); \
    } \
  } while (0)

#define MFMA16() do { \
    _Pragma("unroll") \
    for (int i = 0; i < 4; i++) \
      _Pragma("unroll") \
      for (int j = 0; j < 4; j++) \
        acc[i][j] = __builtin_amdgcn_mfma_f32_16x16x32_bf16(af[i], bfr[j], acc[i][j], 0, 0, 0); \
  } while (0)

  // prologue: stage k-step 0, prefetch A for k-steps 0 and 1
  GLB(0, 0);
  ALOAD(0, 0);
  ALOAD(1, 1);
  APACK(0, 0);
  asm volatile("s_waitcnt vmcnt(0) lgkmcnt(0)" ::: "memory");
  __builtin_amdgcn_s_barrier();
  __builtin_amdgcn_sched_barrier(0);

  // steady state: iter k reads buf k&1; stages B(k+1)+packs A(k+1) into buf^1;
  // issues A-loads(k+2). Barrier waits vmcnt(4): B's gl_lds retired, 4 A-loads fly on.
#define STEP_FULL(KS, BUF, SPACK, SLOAD) do { \
    bf16x8 af[4], bfr[4]; \
    FRAGS(BUF); \
    GLB((KS) + 1, BUF ^ 1); \
    APACK(SPACK, BUF ^ 1); \
    ALOAD((KS) + 2, SLOAD); \
    MFMA16(); \
    asm volatile("s_waitcnt vmcnt(4) lgkmcnt(0)" ::: "memory"); \
    __builtin_amdgcn_s_barrier(); \
    __builtin_amdgcn_sched_barrier(0); \
  } while (0)

  for (int ks = 0; ks < 30; ks += 2) {
    STEP_FULL(ks, 0, 1, 0);
    STEP_FULL(ks + 1, 1, 0, 1);
  }
  {  // k = 30: last prefetch (no A-loads beyond 31) -> full drain
    bf16x8 af[4], bfr[4];
    FRAGS(0);
    GLB(31, 1);
    APACK(1, 1);
    MFMA16();
    asm volatile("s_waitcnt vmcnt(0) lgkmcnt(0)" ::: "memory");
    __builtin_amdgcn_s_barrier();
    __builtin_amdgcn_sched_barrier(0);
  }
  {  // k = 31: compute only
    bf16x8 af[4], bfr[4];
    FRAGS(1);
    MFMA16();
  }
#undef STEP_FULL
#undef MFMA16
#undef FRAGS
#undef APACK
#undef ALOAD
#undef GLB

  // epilogue: C/D layout col=lane&15, row=quad*4+reg
#pragma unroll
  for (int i = 0; i < 4; i++) {
    long rbase = rowbase + wr * 64 + i * 16 + quad * 4;
#pragma unroll
    for (int j = 0; j < 4; j++) {
      int c = wc * 64 + j * 16 + l16;
      float bv = bias[c];
#pragma unroll
      for (int r = 0; r < 4; r++) {
        long grow = rbase + r;
        if (grow < Nrows)
          Out[(size_t)grow * 128 + c] = f2bf(acc[i][j][r] + bv);
      }
    }
  }
}

// ---------------- GCN GEMM: Out[N][128] = bf16( dinv[row] * (A[N][128] @ B[128][128]) ) ----
// K=128: whole A tile (32KB) + whole B (32KB) in LDS, ONE barrier per block.
// 256B rows => linear would be 16-way bank conflict; chunk ^= row&15 makes reads 2-way (free).

__global__ __launch_bounds__(256) void gemm128_kernel(
    const u16* __restrict__ A, const u16* __restrict__ Bt,
    const float* __restrict__ rs, u16* __restrict__ Out, int Nrows)
{
  __shared__ u16 lA[128 * 128];
  __shared__ u16 lB[128 * 128];
  const int t = threadIdx.x;
  const int lane = t & 63;
  const int w = t >> 6;
  const int wr = w >> 1, wc = w & 1;
  const int row0 = blockIdx.x * 128;
  const int quad = lane >> 4;
  const int l16 = lane & 15;

  // stage both tiles via global_load_lds: linear LDS dest, pre-swizzled global source
#pragma unroll
  for (int rp = 0; rp < 8; rp++) {
    int o = (t + rp * 256) * 16;            // linear LDS byte offset
    int row = o >> 8;                       // 256B per row (128 x bf16)
    int io = (o ^ ((row & 15) << 4)) & 255; // swizzled intra-row byte offset
    long grow = (long)row0 + row;
    if (grow >= Nrows) grow = Nrows - 1;    // clamp: no OOB reads on tail block
    gl_lds16((const char*)A + grow * 256 + io, (char*)lA + o);
    gl_lds16((const char*)Bt + row * 256 + io, (char*)lB + o);
  }
  __syncthreads();

  f32x4 acc[4][4];
#pragma unroll
  for (int i = 0; i < 4; i++)
#pragma unroll
    for (int j = 0; j < 4; j++) acc[i][j] = f32x4{0.f, 0.f, 0.f, 0.f};

#pragma unroll
  for (int kk = 0; kk < 4; kk++) {
    bf16x8 af[4], bfr[4];
#pragma unroll
    for (int i = 0; i < 4; i++) {
      int r = wr * 64 + i * 16 + l16;
      int ch = (kk * 4 + quad) ^ (r & 15);
      af[i] = *reinterpret_cast<const bf16x8*>((const char*)lA + r * 256 + ch * 16);
    }
#pragma unroll
    for (int j = 0; j < 4; j++) {
      int c = wc * 64 + j * 16 + l16;
      int ch = (kk * 4 + quad) ^ (c & 15);
      bfr[j] = *reinterpret_cast<const bf16x8*>((const char*)lB + c * 256 + ch * 16);
    }
#pragma unroll
    for (int i = 0; i < 4; i++)
#pragma unroll
      for (int j = 0; j < 4; j++)
        acc[i][j] = __builtin_amdgcn_mfma_f32_16x16x32_bf16(af[i], bfr[j], acc[i][j], 0, 0, 0);
  }

  // epilogue: scale rows by dinv (folds the src-side sym-norm into h')
#pragma unroll
  for (int i = 0; i < 4; i++) {
    int rbase = row0 + wr * 64 + i * 16 + quad * 4;
#pragma unroll
    for (int r = 0; r < 4; r++) {
      int grow = rbase + r;
      if (grow < Nrows) {
        float sc = rs[grow];
#pragma unroll
        for (int j = 0; j < 4; j++) {
          int c = wc * 64 + j * 16 + l16;
          Out[(size_t)grow * 128 + c] = f2bf(acc[i][j][r] * sc);
        }
      }
    }
  }
}

// ---------------- aggregation (+ fused classifier on final layer) ----------------
// h rows are pre-scaled h'[j] = dinv[j]*h[j].
// out[i] = relu( dinv[i] * ( sum_{e:dst=i} h'[col[e]] + h'[i] ) + b )
// One wave per dst row; col indices loaded coalesced (64/load) and shfl-broadcast,
// so gathers have no per-edge load->load address dependency chain.
// FINAL: logits[i] = concat(lm[i], out[i]) @ Wc + bc via per-lane partials + butterfly.

#define BRED(v) do { v += __shfl_xor(v, 1);  v += __shfl_xor(v, 2);  v += __shfl_xor(v, 4); \
                     v += __shfl_xor(v, 8);  v += __shfl_xor(v, 16); v += __shfl_xor(v, 32); } while (0)

template<bool FINAL>
__global__ __launch_bounds__(256) void aggregate_kernel(
    const u16* __restrict__ h, const int* __restrict__ offsets,
    const int* __restrict__ col, const float* __restrict__ dinv,
    const float* __restrict__ bias, u16* __restrict__ outf,
    const u16* __restrict__ lm, const float* __restrict__ Wc,
    const float* __restrict__ bc, float* __restrict__ logits, int N)
{
  int w = threadIdx.x >> 6;
  int lane = threadIdx.x & 63;
  int i = blockIdx.x * 4 + w;
  if (i >= N) return;
  const u32* h32 = (const u32*)h;
  u32 us = h32[(size_t)i * 64 + lane];               // self term h'[i]
  float ax = bf2f(us & 0xffffu), ay = bf2f(us >> 16);
  int s = offsets[i], e = offsets[i + 1];
  for (int base = s; base < e; base += 64) {
    int cnt = e - base; if (cnt > 64) cnt = 64;
    int cj = (base + lane < e) ? col[base + lane] : 0;   // one coalesced load per 64 edges
    int k = 0;
    for (; k + 4 <= cnt; k += 4) {                       // batch-4 gathers for MLP
      int j0 = __shfl(cj, k),     j1 = __shfl(cj, k + 1);
      int j2 = __shfl(cj, k + 2), j3 = __shfl(cj, k + 3);
      u32 u0 = h32[(size_t)j0 * 64 + lane];
      u32 u1 = h32[(size_t)j1 * 64 + lane];
      u32 u2 = h32[(size_t)j2 * 64 + lane];
      u32 u3 = h32[(size_t)j3 * 64 + lane];
      ax += bf2f(u0 & 0xffffu); ay += bf2f(u0 >> 16);
      ax += bf2f(u1 & 0xffffu); ay += bf2f(u1 >> 16);
      ax += bf2f(u2 & 0xffffu); ay += bf2f(u2 >> 16);
      ax += bf2f(u3 & 0xffffu); ay += bf2f(u3 >> 16);
    }
    for (; k < cnt; k++) {
      int j = __shfl(cj, k);
      u32 uu = h32[(size_t)j * 64 + lane];
      ax += bf2f(uu & 0xffffu); ay += bf2f(uu >> 16);
    }
  }
  float di = dinv[i];
  ax = fmaxf(ax * di + bias[lane * 2], 0.f);
  ay = fmaxf(ay * di + bias[lane * 2 + 1], 0.f);
  if (!FINAL) {
    ((u32*)outf)[(size_t)i * 64 + lane] = packbf2(ax, ay);
  } else {
    u32 ul = ((const u32*)lm)[(size_t)i * 64 + lane];
    float lx = bf2f(ul & 0xffffu), ly = bf2f(ul >> 16);
    const float4* W4 = (const float4*)Wc;              // Wc[256][8], 32B per row
    float4 a0 = W4[(2 * lane) * 2],       a1 = W4[(2 * lane) * 2 + 1];        // lm row 2l
    float4 b0 = W4[(2 * lane + 1) * 2],   b1 = W4[(2 * lane + 1) * 2 + 1];    // lm row 2l+1
    float4 c0 = W4[(128 + 2 * lane) * 2], c1 = W4[(128 + 2 * lane) * 2 + 1];  // out row 2l
    float4 d0 = W4[(129 + 2 * lane) * 2], d1 = W4[(129 + 2 * lane) * 2 + 1];  // out row 2l+1
    float s0 = lx * a0.x + ly * b0.x + ax * c0.x + ay * d0.x;
    float s1 = lx * a0.y + ly * b0.y + ax * c0.y + ay * d0.y;
    float s2 = lx * a0.z + ly * b0.z + ax * c0.z + ay * d0.z;
    float s3 = lx * a0.w + ly * b0.w + ax * c0.w + ay * d0.w;
    float s4 = lx * a1.x + ly * b1.x + ax * c1.x + ay * d1.x;
    float s5 = lx * a1.y + ly * b1.y + ax * c1.y + ay * d1.y;
    float s6 = lx * a1.z + ly * b1.z + ax * c1.z + ay * d1.z;
    float s7 = lx * a1.w + ly * b1.w + ax * c1.w + ay * d1.w;
    BRED(s0); BRED(s1); BRED(s2); BRED(s3); BRED(s4); BRED(s5); BRED(s6); BRED(s7);
    if (lane < 8) {
      float v = s0;
      v = (lane == 1) ? s1 : v;
      v = (lane == 2) ? s2 : v;
      v = (lane == 3) ? s3 : v;
      v = (lane == 4) ? s4 : v;
      v = (lane == 5) ? s5 : v;
      v = (lane == 6) ? s6 : v;
      v = (lane == 7) ? s7 : v;
      logits[(size_t)i * 8 + lane] = v + bc[lane];
    }
  }
}
#undef BRED

// ---------------- launcher ----------------

static inline char* bump(char*& p, size_t bytes) {
  char* r = p;
  p += (bytes + 255) & ~(size_t)255;
  return r;
}

extern "C" void kernel_launch(void* const* d_in, const int* in_sizes, int n_in,
                              void* d_out, int out_size, void* d_ws, size_t ws_size,
                              hipStream_t stream) {
  const float* X   = (const float*)d_in[0];   // [N][1024]
  const int*   EI  = (const int*)  d_in[1];   // [2][E]
  const float* Wlm = (const float*)d_in[2];   // [1024][128]
  const float* blm = (const float*)d_in[3];   // [128]
  const float* Wg  = (const float*)d_in[4];   // [L][128][128]
  const float* bg  = (const float*)d_in[5];   // [L][128]
  const float* Wc  = (const float*)d_in[6];   // [256][8]
  const float* bc  = (const float*)d_in[7];   // [8]
  float* out = (float*)d_out;

  const int N = in_sizes[0] / 1024;
  const int E = in_sizes[1] / 2;
  const int L = in_sizes[4] / (128 * 128);

  char* wp = (char*)d_ws;
  int*   counts  = (int*)  bump(wp, (size_t)N * 4);
  int*   offs    = (int*)  bump(wp, (size_t)(N + 1) * 4);
  float* dinv    = (float*)bump(wp, (size_t)N * 4);
  int*   partials= (int*)  bump(wp, 1024 * 4);
  int*   colA    = (int*)  bump(wp, (size_t)E * 4);
  u16*   WlmT    = (u16*)  bump(wp, (size_t)1024 * 128 * 2);
  u16*   WgT     = (u16*)  bump(wp, (size_t)L * 128 * 128 * 2);
  u16*   lmB     = (u16*)  bump(wp, (size_t)N * 128 * 2);
  u16*   hB      = (u16*)  bump(wp, (size_t)N * 128 * 2);
  u16*   featB   = (u16*)  bump(wp, (size_t)N * 128 * 2);

  hipMemsetAsync(counts, 0, (size_t)N * 4, stream);

  const int* srcp = EI;
  const int* dstp = EI + E;

  count_kernel<<<(E + 255) / 256, 256, 0, stream>>>(dstp, counts, E);
  dinv_kernel<<<(N + 255) / 256, 256, 0, stream>>>(counts, dinv, N);

  int NB = (N + 1023) / 1024;   // 98 for N=100000; single-block scan supports NB<=256
  scan_partial<<<NB, 256, 0, stream>>>(counts, partials, N);
  scan_partials_excl<<<1, 256, 0, stream>>>(partials, NB, offs, N, E);
  scan_final<<<NB, 256, 0, stream>>>(counts, partials, offs, N);
  fill_kernel<<<(E + 255) / 256, 256, 0, stream>>>(srcp, dstp, offs, counts, colA, E);

  prep_wlm<<<(1024 * 128 + 255) / 256, 256, 0, stream>>>(Wlm, WlmT);
  prep_wgcn<<<(L * 128 * 128 + 255) / 256, 256, 0, stream>>>(Wg, WgT, L * 128 * 128);

  int GB = (N + 127) / 128;
  gemm_lm_kernel<<<GB, 256, 0, stream>>>(X, WlmT, blm, lmB, N);

  const u16* cur = lmB;
  for (int l = 0; l < L; l++) {
    gemm128_kernel<<<GB, 256, 0, stream>>>(cur, WgT + (size_t)l * 16384, dinv, hB, N);
    if (l < L - 1) {
      aggregate_kernel<false><<<(N + 3) / 4, 256, 0, stream>>>(
          hB, offs, colA, dinv, bg + (size_t)l * 128, featB,
          nullptr, nullptr, nullptr, nullptr, N);
      cur = featB;
    } else {
      aggregate_kernel<true><<<(N + 3) / 4, 256, 0, stream>>>(
          hB, offs, colA, dinv, bg + (size_t)l * 128, nullptr,
          lmB, Wc, bc, out, N);
    }
  }
}

// Round 4
// 886.060 us; speedup vs baseline: 1.0722x; 1.0590x over previous
//
#include <hip/hip_runtime.h>

// LMFreezeConcatModel: lm = X@W_lm+b ; 3x GCNConv(sym-norm, self-loops) ; concat -> W_cls.
// R4: dispatch-count attack. 16 kernels -> 10 via fat-kernel fusion of independent
// work (count rides in lm GEMM; fill rides in gemm128 layer-0; preps merged) and a
// 2-dispatch scan (dinv+scan_partial merged; partials prefix computed inline in
// scan_final). GEMM/aggregate inner loops unchanged from R3 (verified).

using bf16x8 = __attribute__((ext_vector_type(8))) short;
using f32x4  = __attribute__((ext_vector_type(4))) float;
typedef unsigned short u16;
typedef unsigned int   u32;

__device__ __forceinline__ u16 f2bf(float f) {
  u32 u = __builtin_bit_cast(u32, f);
  u += 0x7fffu + ((u >> 16) & 1u);          // round-to-nearest-even
  return (u16)(u >> 16);
}
__device__ __forceinline__ float bf2f(u32 lo16) {
  return __builtin_bit_cast(float, lo16 << 16);
}
__device__ __forceinline__ u32 packbf2(float a, float b) {
  u32 r;                                     // lo = bf16(a), hi = bf16(b), RNE
  asm("v_cvt_pk_bf16_f32 %0, %1, %2" : "=v"(r) : "v"(a), "v"(b));
  return r;
}
__device__ __forceinline__ void gl_lds16(const void* g, void* l) {
  __builtin_amdgcn_global_load_lds(
      (const __attribute__((address_space(1))) void*)g,
      (__attribute__((address_space(3))) void*)l, 16, 0, 0);
}

// ---------------- weight prep (both transposes in one dispatch) ----------------
// blocks [0,512): WlmT (512*256 == 1024*128 exactly); blocks [512,...): WgT.

__global__ void prep_fat(const float* __restrict__ Wlm, u16* __restrict__ WlmT,
                         const float* __restrict__ Wg, u16* __restrict__ WgT, int totalG) {
  int b = blockIdx.x;
  if (b < 512) {
    int idx = b * 256 + threadIdx.x;
    int k = idx >> 7, c = idx & 127;
    WlmT[c * 1024 + k] = f2bf(Wlm[idx]);          // WlmT[col][k]
  } else {
    int idx = (b - 512) * 256 + threadIdx.x;
    if (idx < totalG) {
      int l = idx >> 14; int r = idx & 16383;
      int k = r >> 7, c = r & 127;
      WgT[l * 16384 + c * 128 + k] = f2bf(Wg[idx]);
    }
  }
}

// ---------------- dinv + per-block degree partial sums (one dispatch) ----------------

__global__ void dinv_scanpart(const int* __restrict__ counts, float* __restrict__ dinv,
                              int* __restrict__ partials, int N) {
  __shared__ int sdata[256];
  int t = threadIdx.x;
  int base = blockIdx.x * 1024 + t * 4;
  int s = 0;
#pragma unroll
  for (int i = 0; i < 4; i++) {
    int idx = base + i;
    if (idx < N) {
      int c = counts[idx];
      s += c;
      dinv[idx] = rsqrtf((float)(c + 1));   // +1 self-loop; deg>=1 always
    }
  }
  sdata[t] = s; __syncthreads();
  for (int off = 128; off > 0; off >>= 1) {
    if (t < off) sdata[t] += sdata[t + off];
    __syncthreads();
  }
  if (t == 0) partials[blockIdx.x] = sdata[0];
}

// ---------------- scan_final with inline prefix base (kills scan_partials_excl) --------
// base = sum of partials[k<blockIdx.x] computed by a 256-thread reduce (NB<=256).

__global__ void scan_final2(const int* __restrict__ counts, const int* __restrict__ partials,
                            int* __restrict__ offsets, int N, int E, int NB) {
  __shared__ int sdata[256];
  int t = threadIdx.x;
  int pv = (t < NB && t < (int)blockIdx.x) ? partials[t] : 0;
  sdata[t] = pv; __syncthreads();
  for (int off = 128; off > 0; off >>= 1) {
    if (t < off) sdata[t] += sdata[t + off];
    __syncthreads();
  }
  int bse = sdata[0];
  __syncthreads();

  int bofs = blockIdx.x * 1024 + t * 4;
  int v[4]; int tsum = 0;
#pragma unroll
  for (int i = 0; i < 4; i++) { int idx = bofs + i; v[i] = (idx < N) ? counts[idx] : 0; tsum += v[i]; }
  sdata[t] = tsum; __syncthreads();
  int val = tsum;
  for (int off = 1; off < 256; off <<= 1) {
    int add = (t >= off) ? sdata[t - off] : 0;
    __syncthreads();
    val += add; sdata[t] = val;
    __syncthreads();
  }
  int run = bse + val - tsum;
#pragma unroll
  for (int i = 0; i < 4; i++) { int idx = bofs + i; if (idx < N) offsets[idx] = run; run += v[i]; }
  if (blockIdx.x == 0 && t == 0) offsets[N] = E;
}

// ---------------- lm GEMM (+ fused degree count) ------------------------------------
// Blocks [0,GB): Out[N][128] = bf16(A_f32[N][1024] @ B[1024][128] + bias).
// BM=128 BN=128 BK=32, 4 waves. LDS double-buffered, ONE barrier per K-step,
// depth-2 register prefetch of the A f32 tile, counted s_waitcnt vmcnt(4) so the next
// K-step's 4 A-loads stay in flight across the barrier. 16B-chunk XOR swizzle.
// Blocks [GB,..): degree count (independent CSR chain) rides under the GEMM.

__global__ __launch_bounds__(256) void gemm_lm_count_kernel(
    const float* __restrict__ A, const u16* __restrict__ Bt,
    const float* __restrict__ bias, u16* __restrict__ Out, int Nrows,
    const int* __restrict__ dst, int* __restrict__ counts, int E, int GB)
{
  __shared__ u16 lA[2][128 * 32];
  __shared__ u16 lB[2][128 * 32];
  if ((int)blockIdx.x >= GB) {
    int e = ((int)blockIdx.x - GB) * 256 + threadIdx.x;
    if (e < E) atomicAdd(&counts[dst[e]], 1);
    return;
  }
  const int t = threadIdx.x;
  const int lane = t & 63;
  const int w = t >> 6;
  const int wr = w >> 1, wc = w & 1;
  const long rowbase = (long)blockIdx.x * 128;
  const int quad = lane >> 4;
  const int l16 = lane & 15;

  const int seg0 = t, seg1 = t + 256;
  const int r0 = seg0 >> 2, kq0 = seg0 & 3;
  const int r1 = seg1 >> 2, kq1 = seg1 & 3;
  long g0 = rowbase + r0; if (g0 >= Nrows) g0 = Nrows - 1;
  long g1 = rowbase + r1; if (g1 >= Nrows) g1 = Nrows - 1;
  const float* Ab0 = A + g0 * 1024 + kq0 * 8;
  const float* Ab1 = A + g1 * 1024 + kq1 * 8;
  const int dA0 = (seg0 * 16) ^ ((r0 & 3) << 4);
  const int dA1 = (seg1 * 16) ^ ((r1 & 3) << 4);
  const char* Bsrc0 = (const char*)Bt + (size_t)r0 * 2048 + ((kq0 ^ (r0 & 3)) << 4);
  const char* Bsrc1 = (const char*)Bt + (size_t)r1 * 2048 + ((kq1 ^ (r1 & 3)) << 4);
  const int dB0 = seg0 * 16, dB1 = seg1 * 16;

  f32x4 acc[4][4];
#pragma unroll
  for (int i = 0; i < 4; i++)
#pragma unroll
    for (int j = 0; j < 4; j++) acc[i][j] = f32x4{0.f, 0.f, 0.f, 0.f};

  float4 fa[2][4];   // A prefetch register sets; indices are macro-literal constants only

#define GLB(KS, BUF) do { \
    gl_lds16(Bsrc0 + (size_t)(KS) * 64, (char*)lB[BUF] + dB0); \
    gl_lds16(Bsrc1 + (size_t)(KS) * 64, (char*)lB[BUF] + dB1); \
  } while (0)

#define ALOAD(KS, S) do { \
    fa[S][0] = *reinterpret_cast<const float4*>(Ab0 + (KS) * 32); \
    fa[S][1] = *reinterpret_cast<const float4*>(Ab0 + (KS) * 32 + 4); \
    fa[S][2] = *reinterpret_cast<const float4*>(Ab1 + (KS) * 32); \
    fa[S][3] = *reinterpret_cast<const float4*>(Ab1 + (KS) * 32 + 4); \
  } while (0)

#define APACK(S, BUF) do { \
    uint4 pk0, pk1; \
    pk0.x = packbf2(fa[S][0].x, fa[S][0].y); pk0.y = packbf2(fa[S][0].z, fa[S][0].w); \
    pk0.z = packbf2(fa[S][1].x, fa[S][1].y); pk0.w = packbf2(fa[S][1].z, fa[S][1].w); \
    pk1.x = packbf2(fa[S][2].x, fa[S][2].y); pk1.y = packbf2(fa[S][2].z, fa[S][2].w); \
    pk1.z = packbf2(fa[S][3].x, fa[S][3].y); pk1.w = packbf2(fa[S][3].z, fa[S][3].w); \
    *reinterpret_cast<uint4*>((char*)lA[BUF] + dA0) = pk0; \
    *reinterpret_cast<uint4*>((char*)lA[BUF] + dA1) = pk1; \
  } while (0)

#define FRAGS(BUF) do { \
    _Pragma("unroll") \
    for (int i = 0; i < 4; i++) { \
      int r = wr * 64 + i * 16 + l16; \
      af[i] = *reinterpret_cast<const bf16x8*>( \
          (const char*)lA[BUF] + r * 64 + ((quad ^ (r & 3)) << 4)); \
    } \
    _Pragma("unroll") \
    for (int j = 0; j < 4; j++) { \
      int c = wc * 64 + j * 16 + l16; \
      bfr[j] = *reinterpret_cast<const bf16x8*>( \
          (const char*)lB[BUF] + c * 64 + ((quad ^ (c & 3)) << 4)); \
    } \
  } while (0)

#define MFMA16() do { \
    _Pragma("unroll") \
    for (int i = 0; i < 4; i++) \
      _Pragma("unroll") \
      for (int j = 0; j < 4; j++) \
        acc[i][j] = __builtin_amdgcn_mfma_f32_16x16x32_bf16(af[i], bfr[j], acc[i][j], 0, 0, 0); \
  } while (0)

  // prologue: stage k-step 0, prefetch A for k-steps 0 and 1
  GLB(0, 0);
  ALOAD(0, 0);
  ALOAD(1, 1);
  APACK(0, 0);
  asm volatile("s_waitcnt vmcnt(0) lgkmcnt(0)" ::: "memory");
  __builtin_amdgcn_s_barrier();
  __builtin_amdgcn_sched_barrier(0);

#define STEP_FULL(KS, BUF, SPACK, SLOAD) do { \
    bf16x8 af[4], bfr[4]; \
    FRAGS(BUF); \
    GLB((KS) + 1, BUF ^ 1); \
    APACK(SPACK, BUF ^ 1); \
    ALOAD((KS) + 2, SLOAD); \
    MFMA16(); \
    asm volatile("s_waitcnt vmcnt(4) lgkmcnt(0)" ::: "memory"); \
    __builtin_amdgcn_s_barrier(); \
    __builtin_amdgcn_sched_barrier(0); \
  } while (0)

  for (int ks = 0; ks < 30; ks += 2) {
    STEP_FULL(ks, 0, 1, 0);
    STEP_FULL(ks + 1, 1, 0, 1);
  }
  {  // k = 30: last prefetch -> full drain
    bf16x8 af[4], bfr[4];
    FRAGS(0);
    GLB(31, 1);
    APACK(1, 1);
    MFMA16();
    asm volatile("s_waitcnt vmcnt(0) lgkmcnt(0)" ::: "memory");
    __builtin_amdgcn_s_barrier();
    __builtin_amdgcn_sched_barrier(0);
  }
  {  // k = 31: compute only
    bf16x8 af[4], bfr[4];
    FRAGS(1);
    MFMA16();
  }
#undef STEP_FULL
#undef MFMA16
#undef FRAGS
#undef APACK
#undef ALOAD
#undef GLB

  // epilogue: C/D layout col=lane&15, row=quad*4+reg
#pragma unroll
  for (int i = 0; i < 4; i++) {
    long rbase = rowbase + wr * 64 + i * 16 + quad * 4;
#pragma unroll
    for (int j = 0; j < 4; j++) {
      int c = wc * 64 + j * 16 + l16;
      float bv = bias[c];
#pragma unroll
      for (int r = 0; r < 4; r++) {
        long grow = rbase + r;
        if (grow < Nrows)
          Out[(size_t)grow * 128 + c] = f2bf(acc[i][j][r] + bv);
      }
    }
  }
}

// ---------------- GCN GEMM body: Out[N][128] = bf16( dinv[row]*(A[N][128]@B[128][128]) ) ----
// K=128: whole A tile (32KB) + whole B (32KB) in LDS, ONE barrier.
// chunk ^= row&15 swizzle: frag reads 2-way conflict max (free).

__device__ __forceinline__ void gemm128_body(
    u16* lA, u16* lB, int bid,
    const u16* __restrict__ A, const u16* __restrict__ Bt,
    const float* __restrict__ rs, u16* __restrict__ Out, int Nrows)
{
  const int t = threadIdx.x;
  const int lane = t & 63;
  const int w = t >> 6;
  const int wr = w >> 1, wc = w & 1;
  const int row0 = bid * 128;
  const int quad = lane >> 4;
  const int l16 = lane & 15;

#pragma unroll
  for (int rp = 0; rp < 8; rp++) {
    int o = (t + rp * 256) * 16;            // linear LDS byte offset
    int row = o >> 8;                       // 256B per row
    int io = (o ^ ((row & 15) << 4)) & 255; // swizzled intra-row byte offset
    long grow = (long)row0 + row;
    if (grow >= Nrows) grow = Nrows - 1;
    gl_lds16((const char*)A + grow * 256 + io, (char*)lA + o);
    gl_lds16((const char*)Bt + row * 256 + io, (char*)lB + o);
  }
  __syncthreads();

  f32x4 acc[4][4];
#pragma unroll
  for (int i = 0; i < 4; i++)
#pragma unroll
    for (int j = 0; j < 4; j++) acc[i][j] = f32x4{0.f, 0.f, 0.f, 0.f};

#pragma unroll
  for (int kk = 0; kk < 4; kk++) {
    bf16x8 af[4], bfr[4];
#pragma unroll
    for (int i = 0; i < 4; i++) {
      int r = wr * 64 + i * 16 + l16;
      int ch = (kk * 4 + quad) ^ (r & 15);
      af[i] = *reinterpret_cast<const bf16x8*>((const char*)lA + r * 256 + ch * 16);
    }
#pragma unroll
    for (int j = 0; j < 4; j++) {
      int c = wc * 64 + j * 16 + l16;
      int ch = (kk * 4 + quad) ^ (c & 15);
      bfr[j] = *reinterpret_cast<const bf16x8*>((const char*)lB + c * 256 + ch * 16);
    }
#pragma unroll
    for (int i = 0; i < 4; i++)
#pragma unroll
      for (int j = 0; j < 4; j++)
        acc[i][j] = __builtin_amdgcn_mfma_f32_16x16x32_bf16(af[i], bfr[j], acc[i][j], 0, 0, 0);
  }

#pragma unroll
  for (int i = 0; i < 4; i++) {
    int rbase = row0 + wr * 64 + i * 16 + quad * 4;
#pragma unroll
    for (int r = 0; r < 4; r++) {
      int grow = rbase + r;
      if (grow < Nrows) {
        float sc = rs[grow];
#pragma unroll
        for (int j = 0; j < 4; j++) {
          int c = wc * 64 + j * 16 + l16;
          Out[(size_t)grow * 128 + c] = f2bf(acc[i][j][r] * sc);
        }
      }
    }
  }
}

__global__ __launch_bounds__(256) void gemm128_kernel(
    const u16* __restrict__ A, const u16* __restrict__ Bt,
    const float* __restrict__ rs, u16* __restrict__ Out, int Nrows)
{
  __shared__ u16 lA[128 * 128];
  __shared__ u16 lB[128 * 128];
  gemm128_body(lA, lB, blockIdx.x, A, Bt, rs, Out, Nrows);
}

// layer-0 GEMM with the (independent) CSR fill riding in extra blocks.
__global__ __launch_bounds__(256) void gemm128_fill_kernel(
    const u16* __restrict__ A, const u16* __restrict__ Bt,
    const float* __restrict__ rs, u16* __restrict__ Out, int Nrows,
    const int* __restrict__ src, const int* __restrict__ dst,
    const int* __restrict__ offsets, int* __restrict__ counts,
    int* __restrict__ col, int E, int GB)
{
  __shared__ u16 lA[128 * 128];
  __shared__ u16 lB[128 * 128];
  if ((int)blockIdx.x >= GB) {
    // fill claims slots by decrementing counts (degree) -> offs[d]..offs[d]+deg-1.
    int e = ((int)blockIdx.x - GB) * 256 + threadIdx.x;
    if (e < E) {
      int d = dst[e];
      int p = offsets[d] + atomicSub(&counts[d], 1) - 1;
      col[p] = src[e];
    }
    return;
  }
  gemm128_body(lA, lB, blockIdx.x, A, Bt, rs, Out, Nrows);
}

// ---------------- aggregation (+ fused classifier on final layer) ----------------
// h rows are pre-scaled h'[j] = dinv[j]*h[j].
// out[i] = relu( dinv[i] * ( sum_{e:dst=i} h'[col[e]] + h'[i] ) + b )
// One wave per dst row; col indices loaded coalesced and shfl-broadcast.
// FINAL: logits[i] = concat(lm[i], out[i]) @ Wc + bc via per-lane partials + butterfly.

#define BRED(v) do { v += __shfl_xor(v, 1);  v += __shfl_xor(v, 2);  v += __shfl_xor(v, 4); \
                     v += __shfl_xor(v, 8);  v += __shfl_xor(v, 16); v += __shfl_xor(v, 32); } while (0)

template<bool FINAL>
__global__ __launch_bounds__(256) void aggregate_kernel(
    const u16* __restrict__ h, const int* __restrict__ offsets,
    const int* __restrict__ col, const float* __restrict__ dinv,
    const float* __restrict__ bias, u16* __restrict__ outf,
    const u16* __restrict__ lm, const float* __restrict__ Wc,
    const float* __restrict__ bc, float* __restrict__ logits, int N)
{
  int w = threadIdx.x >> 6;
  int lane = threadIdx.x & 63;
  int i = blockIdx.x * 4 + w;
  if (i >= N) return;
  const u32* h32 = (const u32*)h;
  u32 us = h32[(size_t)i * 64 + lane];               // self term h'[i]
  float ax = bf2f(us & 0xffffu), ay = bf2f(us >> 16);
  int s = offsets[i], e = offsets[i + 1];
  for (int base = s; base < e; base += 64) {
    int cnt = e - base; if (cnt > 64) cnt = 64;
    int cj = (base + lane < e) ? col[base + lane] : 0;   // one coalesced load per 64 edges
    int k = 0;
    for (; k + 4 <= cnt; k += 4) {                       // batch-4 gathers for MLP
      int j0 = __shfl(cj, k),     j1 = __shfl(cj, k + 1);
      int j2 = __shfl(cj, k + 2), j3 = __shfl(cj, k + 3);
      u32 u0 = h32[(size_t)j0 * 64 + lane];
      u32 u1 = h32[(size_t)j1 * 64 + lane];
      u32 u2 = h32[(size_t)j2 * 64 + lane];
      u32 u3 = h32[(size_t)j3 * 64 + lane];
      ax += bf2f(u0 & 0xffffu); ay += bf2f(u0 >> 16);
      ax += bf2f(u1 & 0xffffu); ay += bf2f(u1 >> 16);
      ax += bf2f(u2 & 0xffffu); ay += bf2f(u2 >> 16);
      ax += bf2f(u3 & 0xffffu); ay += bf2f(u3 >> 16);
    }
    for (; k < cnt; k++) {
      int j = __shfl(cj, k);
      u32 uu = h32[(size_t)j * 64 + lane];
      ax += bf2f(uu & 0xffffu); ay += bf2f(uu >> 16);
    }
  }
  float di = dinv[i];
  ax = fmaxf(ax * di + bias[lane * 2], 0.f);
  ay = fmaxf(ay * di + bias[lane * 2 + 1], 0.f);
  if (!FINAL) {
    ((u32*)outf)[(size_t)i * 64 + lane] = packbf2(ax, ay);
  } else {
    u32 ul = ((const u32*)lm)[(size_t)i * 64 + lane];
    float lx = bf2f(ul & 0xffffu), ly = bf2f(ul >> 16);
    const float4* W4 = (const float4*)Wc;              // Wc[256][8], 32B per row
    float4 a0 = W4[(2 * lane) * 2],       a1 = W4[(2 * lane) * 2 + 1];
    float4 b0 = W4[(2 * lane + 1) * 2],   b1 = W4[(2 * lane + 1) * 2 + 1];
    float4 c0 = W4[(128 + 2 * lane) * 2], c1 = W4[(128 + 2 * lane) * 2 + 1];
    float4 d0 = W4[(129 + 2 * lane) * 2], d1 = W4[(129 + 2 * lane) * 2 + 1];
    float s0 = lx * a0.x + ly * b0.x + ax * c0.x + ay * d0.x;
    float s1 = lx * a0.y + ly * b0.y + ax * c0.y + ay * d0.y;
    float s2 = lx * a0.z + ly * b0.z + ax * c0.z + ay * d0.z;
    float s3 = lx * a0.w + ly * b0.w + ax * c0.w + ay * d0.w;
    float s4 = lx * a1.x + ly * b1.x + ax * c1.x + ay * d1.x;
    float s5 = lx * a1.y + ly * b1.y + ax * c1.y + ay * d1.y;
    float s6 = lx * a1.z + ly * b1.z + ax * c1.z + ay * d1.z;
    float s7 = lx * a1.w + ly * b1.w + ax * c1.w + ay * d1.w;
    BRED(s0); BRED(s1); BRED(s2); BRED(s3); BRED(s4); BRED(s5); BRED(s6); BRED(s7);
    if (lane < 8) {
      float v = s0;
      v = (lane == 1) ? s1 : v;
      v = (lane == 2) ? s2 : v;
      v = (lane == 3) ? s3 : v;
      v = (lane == 4) ? s4 : v;
      v = (lane == 5) ? s5 : v;
      v = (lane == 6) ? s6 : v;
      v = (lane == 7) ? s7 : v;
      logits[(size_t)i * 8 + lane] = v + bc[lane];
    }
  }
}
#undef BRED

// ---------------- launcher ----------------

static inline char* bump(char*& p, size_t bytes) {
  char* r = p;
  p += (bytes + 255) & ~(size_t)255;
  return r;
}

extern "C" void kernel_launch(void* const* d_in, const int* in_sizes, int n_in,
                              void* d_out, int out_size, void* d_ws, size_t ws_size,
                              hipStream_t stream) {
  const float* X   = (const float*)d_in[0];   // [N][1024]
  const int*   EI  = (const int*)  d_in[1];   // [2][E]
  const float* Wlm = (const float*)d_in[2];   // [1024][128]
  const float* blm = (const float*)d_in[3];   // [128]
  const float* Wg  = (const float*)d_in[4];   // [L][128][128]
  const float* bg  = (const float*)d_in[5];   // [L][128]
  const float* Wc  = (const float*)d_in[6];   // [256][8]
  const float* bc  = (const float*)d_in[7];   // [8]
  float* out = (float*)d_out;

  const int N = in_sizes[0] / 1024;
  const int E = in_sizes[1] / 2;
  const int L = in_sizes[4] / (128 * 128);

  char* wp = (char*)d_ws;
  int*   counts  = (int*)  bump(wp, (size_t)N * 4);
  int*   offs    = (int*)  bump(wp, (size_t)(N + 1) * 4);
  float* dinv    = (float*)bump(wp, (size_t)N * 4);
  int*   partials= (int*)  bump(wp, 1024 * 4);
  int*   colA    = (int*)  bump(wp, (size_t)E * 4);
  u16*   WlmT    = (u16*)  bump(wp, (size_t)1024 * 128 * 2);
  u16*   WgT     = (u16*)  bump(wp, (size_t)L * 128 * 128 * 2);
  u16*   lmB     = (u16*)  bump(wp, (size_t)N * 128 * 2);
  u16*   hB      = (u16*)  bump(wp, (size_t)N * 128 * 2);
  u16*   featB   = (u16*)  bump(wp, (size_t)N * 128 * 2);

  hipMemsetAsync(counts, 0, (size_t)N * 4, stream);

  const int* srcp = EI;
  const int* dstp = EI + E;

  const int GB = (N + 127) / 128;        // 782
  const int CB = (E + 255) / 256;        // 3907
  const int NB = (N + 1023) / 1024;      // 98 (<=256 required by scan_final2)
  const int PGB = (L * 128 * 128 + 255) / 256;

  // 1. both weight transposes
  prep_fat<<<512 + PGB, 256, 0, stream>>>(Wlm, WlmT, Wg, WgT, L * 128 * 128);
  // 2. lm GEMM + degree count (independent, fused)
  gemm_lm_count_kernel<<<GB + CB, 256, 0, stream>>>(X, WlmT, blm, lmB, N, dstp, counts, E, GB);
  // 3. dinv + per-block partial sums
  dinv_scanpart<<<NB, 256, 0, stream>>>(counts, dinv, partials, N);
  // 4. offsets (inline prefix of partials)
  scan_final2<<<NB, 256, 0, stream>>>(counts, partials, offs, N, E, NB);
  // 5. layer-0 GEMM + CSR fill (independent, fused)
  gemm128_fill_kernel<<<GB + CB, 256, 0, stream>>>(lmB, WgT, dinv, hB, N,
                                                   srcp, dstp, offs, counts, colA, E, GB);

  const u16* cur;
  // 6-10. aggregate / gemm chain
  aggregate_kernel<false><<<(N + 3) / 4, 256, 0, stream>>>(
      hB, offs, colA, dinv, bg, featB, nullptr, nullptr, nullptr, nullptr, N);
  cur = featB;
  for (int l = 1; l < L; l++) {
    gemm128_kernel<<<GB, 256, 0, stream>>>(cur, WgT + (size_t)l * 16384, dinv, hB, N);
    if (l < L - 1) {
      aggregate_kernel<false><<<(N + 3) / 4, 256, 0, stream>>>(
          hB, offs, colA, dinv, bg + (size_t)l * 128, featB,
          nullptr, nullptr, nullptr, nullptr, N);
      cur = featB;
    } else {
      aggregate_kernel<true><<<(N + 3) / 4, 256, 0, stream>>>(
          hB, offs, colA, dinv, bg + (size_t)l * 128, nullptr,
          lmB, Wc, bc, out, N);
    }
  }
}